// Round 1
// 171.723 us; speedup vs baseline: 1.1118x; 1.1118x over previous
//
#include <hip/hip_runtime.h>
#include <hip/hip_bf16.h>
#include <string.h>

typedef __hip_bfloat16 bf16;
typedef __attribute__((ext_vector_type(8))) short short8;
typedef __attribute__((ext_vector_type(4))) short short4v;
typedef __attribute__((ext_vector_type(4))) float f32x4;

__device__ __forceinline__ float b2f(bf16 v) { return __bfloat162float(v); }
__device__ __forceinline__ bf16  f2b(float v) { return __float2bfloat16(v); }
__device__ __forceinline__ float s2f(short s) {
    return __uint_as_float(((unsigned)(unsigned short)s) << 16);
}
__device__ __forceinline__ short f2s(float v) {
    bf16 t = f2b(v); short s; __builtin_memcpy(&s, &t, 2); return s;
}

#define CC 256
#define HWD 16384    // 128*128

// ---------------------------------------------------------------------------
// K01 (fused k0+k1): transpose x (b,256,4096) fp32 -> xpm (b,4096,256) bf16
// via swizzled LDS tile, then MFMA the off/ast GEMM straight from LDS.
// grid 256 = 4 b * 64 tiles(64 px); 256 threads.
// LDS tile layout: row = pixel (256 shorts = 32 x 16B slots), slot index
// XOR-swizzled with (row&7) so MFMA ds_read_b128 fragments are conflict-free.
// ---------------------------------------------------------------------------
__global__ __launch_bounds__(256) void k01_xpose_off(const float* __restrict__ x,
        const float* __restrict__ w_off, const float* __restrict__ b_off,
        const float* __restrict__ w_ast, const float* __restrict__ b_ast,
        bf16* __restrict__ xpm, float* __restrict__ offpm)
{
    __shared__ __align__(16) short tileS[64 * 256];   // 32 KB, swizzled
    const int b = blockIdx.x >> 6;
    const int p0 = (blockIdx.x & 63) << 6;
    const int lane = threadIdx.x & 63;
    const int wave = threadIdx.x >> 6;
    const int n = lane & 15, quad = lane >> 4;

    // --- B fragments for off/ast GEMM (global weights; issue early) ---
    const int jb = wave << 4;
    const int j = jb + n, oc = j >> 1, kind = j & 1;
    short8 bfrag[8];
    const float* wrow = (kind ? w_ast : w_off) + oc * 256 + quad * 8;
#pragma unroll
    for (int kc = 0; kc < 8; ++kc) {
        float4 lo = *(const float4*)(wrow + kc * 32);
        float4 hi = *(const float4*)(wrow + kc * 32 + 4);
        short8 f;
        f[0] = f2s(lo.x); f[1] = f2s(lo.y); f[2] = f2s(lo.z); f[3] = f2s(lo.w);
        f[4] = f2s(hi.x); f[5] = f2s(hi.y); f[6] = f2s(hi.z); f[7] = f2s(hi.w);
        bfrag[kc] = f;
    }
    float bias = kind ? b_ast[oc] : b_off[oc];

    // --- phase 1: fill swizzled LDS tile (pixel-major) ---
    {
        const float* xb = x + ((size_t)b << 20);
        const int lp = lane;          // pixel within tile
        const int c0 = wave;          // channel quarter
#pragma unroll
        for (int gg = 0; gg < 8; ++gg) {
            int cbase = (c0 << 6) + (gg << 3);
            short8 pk;
#pragma unroll
            for (int jj = 0; jj < 8; ++jj)
                pk[jj] = f2s(xb[((size_t)(cbase + jj) << 12) + p0 + lp]);
            int slot = (cbase >> 3) ^ (lp & 7);
            *(short8*)&tileS[(lp << 8) + (slot << 3)] = pk;
        }
    }
    __syncthreads();

    // --- phase 2: coalesced xpm store from LDS ---
    {
        short* ob = (short*)xpm + ((size_t)((b << 12) + p0) << 8);
#pragma unroll
        for (int rr = 0; rr < 16; ++rr) {
            int r = (wave << 4) + rr;
            short4v v = *(const short4v*)&tileS[(r << 8)
                        + ((((lane >> 1) ^ (r & 7)) << 3) | ((lane & 1) << 2))];
            *(short4v*)(ob + ((size_t)r << 8) + (lane << 2)) = v;
        }
    }

    // --- phase 3: MFMA GEMM from LDS, gated epilogue -> offpm ---
    float* obase = offpm + ((size_t)(b << 12) << 5);
#pragma unroll
    for (int mt = 0; mt < 4; mt += 2) {
        f32x4 acc0 = {0.f, 0.f, 0.f, 0.f};
        f32x4 acc1 = {0.f, 0.f, 0.f, 0.f};
#pragma unroll
        for (int kc = 0; kc < 8; ++kc) {
            int slot = (((kc << 2) + quad) ^ (n & 7)) << 3;
            short8 a0 = *(const short8*)&tileS[((mt * 16 + n) << 8) + slot];
            short8 a1 = *(const short8*)&tileS[((mt * 16 + 16 + n) << 8) + slot];
            acc0 = __builtin_amdgcn_mfma_f32_16x16x32_bf16(a0, bfrag[kc], acc0, 0, 0, 0);
            acc1 = __builtin_amdgcn_mfma_f32_16x16x32_bf16(a1, bfrag[kc], acc1, 0, 0, 0);
        }
#pragma unroll
        for (int r = 0; r < 4; ++r) {
            float v0 = acc0[r] + bias;
            float v1 = acc1[r] + bias;
            float p0v = __shfl_xor(v0, 1, 64);
            float p1v = __shfl_xor(v1, 1, 64);
            if (!(n & 1)) {
                int px = p0 + mt * 16 + quad * 4 + r;
                obase[((size_t)px << 5) + oc] = v0 * (1.f / (1.f + expf(-p0v)));
                obase[((size_t)(px + 16) << 5) + oc] = v1 * (1.f / (1.f + expf(-p1v)));
            }
        }
    }
}

// ---------------------------------------------------------------------------
// K23 (fused k2+k3): def_sample 64 up-pixels per block into swizzled LDS
// (+ global xup for k4b), then comp MFMA from LDS, then kern/toff epilogue.
// grid 1024 = 4 b * 256 tiles(64 px); 4 waves x 16 px gather each.
// LDS tile reused (barrier-separated) as the smc[64][65] float buffer.
// ---------------------------------------------------------------------------
__global__ __launch_bounds__(256) void k23_defsample_comp(
        const bf16* __restrict__ xpm, const float* __restrict__ offpm,
        const float* __restrict__ cw, const float* __restrict__ cb,
        const float* __restrict__ fw_g, const float* __restrict__ fb,
        const float* __restrict__ tw, const float* __restrict__ tb,
        const float* __restrict__ taw, const float* __restrict__ tab,
        bf16* __restrict__ xup, bf16* __restrict__ kern, float* __restrict__ toff)
{
    __shared__ __align__(16) short xupS[64 * 256];   // 32 KB; later smc[64][65] f32
    __shared__ __align__(16) float fwS[64 * 12];
    __shared__ __align__(16) float swS[64 * 16];
    for (int i = threadIdx.x; i < 64 * 12; i += 256) {
        int c = i / 12, k = i % 12;
        fwS[i] = (k < 9) ? fw_g[k * 64 + c] : 0.f;
    }
    for (int i = threadIdx.x; i < 64 * 16; i += 256) {
        int c = i >> 4, jj = i & 15;
        int oc = jj >> 1, kind = jj & 1;
        swS[i] = kind ? taw[oc * 64 + c] : tw[oc * 64 + c];
    }

    const int b = blockIdx.x >> 8;
    const int hw0 = (blockIdx.x & 255) << 6;
    const int lane = threadIdx.x & 63;
    const int wave = threadIdx.x >> 6;
    const int n = lane & 15, quad = lane >> 4;
    const int ocb = wave << 4;

    // --- B fragments for comp GEMM (issue early; latency hides under gather) ---
    short8 bfrag[8];
    const float* wrow = cw + (ocb + n) * 256 + quad * 8;
#pragma unroll
    for (int kc = 0; kc < 8; ++kc) {
        float4 lo = *(const float4*)(wrow + kc * 32);
        float4 hi = *(const float4*)(wrow + kc * 32 + 4);
        short8 f;
        f[0] = f2s(lo.x); f[1] = f2s(lo.y); f[2] = f2s(lo.z); f[3] = f2s(lo.w);
        f[4] = f2s(hi.x); f[5] = f2s(hi.y); f[6] = f2s(hi.z); f[7] = f2s(hi.w);
        bfrag[kc] = f;
    }
    float bias = cb[ocb + n];

    // --- phase 1: gather 16 up-pixels per wave; write global + swizzled LDS ---
    {
        const short* xsrc = (const short*)xpm + ((size_t)b << 20);
        const int e = lane << 2;              // 4-channel chunk (shorts)
        const int g = lane >> 4;
#pragma unroll 2
        for (int i = 0; i < 16; ++i) {
            int pp = (wave << 4) + i;
            int hw = hw0 + pp;
            int hy = hw >> 7, wx = hw & 127;
            int h = hy >> 1, w = wx >> 1;
            int och = (g << 3) + ((hy & 1) << 2) + ((wx & 1) << 1);
            const float* orow = offpm + ((size_t)((b << 12) + (h << 6) + w) << 5);
            float ox = orow[och], oy = orow[och + 1];
            float ix = (wx + 0.5f + ox) * 0.5f - 0.5f;
            float iy = (hy + 0.5f + oy) * 0.5f - 0.5f;
            ix = fminf(fmaxf(ix, 0.f), 63.f);
            iy = fminf(fmaxf(iy, 0.f), 63.f);
            float x0f = floorf(ix), y0f = floorf(iy);
            float fx = ix - x0f, fy = iy - y0f;
            int x0 = (int)x0f, y0 = (int)y0f;
            int x1 = min(x0 + 1, 63), y1 = min(y0 + 1, 63);
            float w00 = (1.f - fx) * (1.f - fy), w01 = fx * (1.f - fy);
            float w10 = (1.f - fx) * fy,        w11 = fx * fy;
            short4v v00 = *(const short4v*)(xsrc + (((size_t)(y0 << 6) + x0) << 8) + e);
            short4v v01 = *(const short4v*)(xsrc + (((size_t)(y0 << 6) + x1) << 8) + e);
            short4v v10 = *(const short4v*)(xsrc + (((size_t)(y1 << 6) + x0) << 8) + e);
            short4v v11 = *(const short4v*)(xsrc + (((size_t)(y1 << 6) + x1) << 8) + e);
            short4v pk;
#pragma unroll
            for (int jj = 0; jj < 4; ++jj) {
                float v = w00 * s2f(v00[jj]) + w01 * s2f(v01[jj])
                        + w10 * s2f(v10[jj]) + w11 * s2f(v11[jj]);
                pk[jj] = f2s(v);
            }
            *(short4v*)((short*)xup + (((size_t)((b << 14) + hw)) << 8) + e) = pk;
            *(short4v*)&xupS[(pp << 8)
                    + ((((e >> 3) ^ (pp & 7)) << 3) | (e & 4))] = pk;
        }
    }
    __syncthreads();

    // --- phase 2: comp MFMA from swizzled LDS (accs stay in registers) ---
    f32x4 accA0 = {0.f,0.f,0.f,0.f}, accA1 = {0.f,0.f,0.f,0.f};
    f32x4 accB0 = {0.f,0.f,0.f,0.f}, accB1 = {0.f,0.f,0.f,0.f};
#pragma unroll
    for (int kc = 0; kc < 8; ++kc) {
        int slot = (((kc << 2) + quad) ^ (n & 7)) << 3;
        short8 a0 = *(const short8*)&xupS[((     n) << 8) + slot];
        short8 a1 = *(const short8*)&xupS[((16 + n) << 8) + slot];
        short8 a2 = *(const short8*)&xupS[((32 + n) << 8) + slot];
        short8 a3 = *(const short8*)&xupS[((48 + n) << 8) + slot];
        accA0 = __builtin_amdgcn_mfma_f32_16x16x32_bf16(a0, bfrag[kc], accA0, 0, 0, 0);
        accA1 = __builtin_amdgcn_mfma_f32_16x16x32_bf16(a1, bfrag[kc], accA1, 0, 0, 0);
        accB0 = __builtin_amdgcn_mfma_f32_16x16x32_bf16(a2, bfrag[kc], accB0, 0, 0, 0);
        accB1 = __builtin_amdgcn_mfma_f32_16x16x32_bf16(a3, bfrag[kc], accB1, 0, 0, 0);
    }
    __syncthreads();   // all waves done READING xupS; safe to overwrite as smc

    float (*smc)[65] = (float (*)[65])xupS;   // 64*65*4 = 16.6 KB <= 32 KB
#pragma unroll
    for (int r = 0; r < 4; ++r) {
        smc[     quad * 4 + r][ocb + n] = accA0[r] + bias;
        smc[16 + quad * 4 + r][ocb + n] = accA1[r] + bias;
        smc[32 + quad * 4 + r][ocb + n] = accB0[r] + bias;
        smc[48 + quad * 4 + r][ocb + n] = accB1[r] + bias;
    }
    __syncthreads();

    // --- phase 3: kern softmax (wave 0) / toff gated conv (waves 1..3) ---
    const int px = threadIdx.x & 63;
    const int q = threadIdx.x >> 6;
    const int hw = hw0 + px;
    if (q == 0) {
        float a[9];
#pragma unroll
        for (int k = 0; k < 9; ++k) a[k] = fb[k];
        for (int c = 0; c < 64; ++c) {
            float v = smc[px][c];
            const float4* wr = reinterpret_cast<const float4*>(&fwS[c * 12]);
            float4 w0 = wr[0], w1 = wr[1];
            float w8 = fwS[c * 12 + 8];
            a[0] += v * w0.x; a[1] += v * w0.y; a[2] += v * w0.z; a[3] += v * w0.w;
            a[4] += v * w1.x; a[5] += v * w1.y; a[6] += v * w1.z; a[7] += v * w1.w;
            a[8] += v * w8;
        }
        float mx = a[0];
#pragma unroll
        for (int k = 1; k < 9; ++k) mx = fmaxf(mx, a[k]);
        float s = 0.f;
#pragma unroll
        for (int k = 0; k < 9; ++k) { a[k] = expf(a[k] - mx); s += a[k]; }
        float inv = 1.f / s;
        short* kr = (short*)kern + ((size_t)((b << 14) + hw) << 4);
        short8 pk;
#pragma unroll
        for (int k = 0; k < 8; ++k) pk[k] = f2s(a[k] * inv);
        *(short8*)kr = pk;
        kr[8] = f2s(a[8] * inv);
    } else {
        const int oc0 = (q == 3) ? 6 : (q - 1) * 3;
        const int noc = (q == 3) ? 2 : 3;
        float o[3], aa[3];
        for (int i = 0; i < noc; ++i) { o[i] = tb[oc0 + i]; aa[i] = tab[oc0 + i]; }
        for (int c = 0; c < 64; ++c) {
            float v = smc[px][c];
            const float* wr = &swS[c << 4];
#pragma unroll 3
            for (int i = 0; i < noc; ++i) {
                o[i]  += v * wr[2 * (oc0 + i)];
                aa[i] += v * wr[2 * (oc0 + i) + 1];
            }
        }
        for (int i = 0; i < noc; ++i)
            toff[((size_t)((b << 3) + oc0 + i) << 14) + hw] =
                o[i] * (1.f / (1.f + expf(-aa[i])));
    }
}

// ---------------------------------------------------------------------------
// K4b: xfilt_pm[b][hw][c] = sum_k kern[b][hw][k] * xup_pm[b][tap_k(hw)][c]
// ---------------------------------------------------------------------------
__global__ __launch_bounds__(256) void k4b_apply(const bf16* __restrict__ xup,
        const bf16* __restrict__ kern, bf16* __restrict__ xfilt)
{
    int t = blockIdx.x * 256 + threadIdx.x;
    int chunk = t & 31;
    int hw = (t >> 5) & 16383;
    int b = t >> 19;
    int h = hw >> 7, w = hw & 127;

    const short* kr = (const short*)kern + ((size_t)(b * HWD + hw) << 4);
    short8 k8 = *(const short8*)kr;
    float wk[9];
#pragma unroll
    for (int k = 0; k < 8; ++k) wk[k] = s2f(k8[k]);
    wk[8] = s2f(kr[8]);

    float ymask[3] = { h > 0 ? 1.f : 0.f, 1.f, h < 127 ? 1.f : 0.f };
    float xmask[3] = { w > 0 ? 1.f : 0.f, 1.f, w < 127 ? 1.f : 0.f };
    int hy[3] = { (max(h - 1, 0)) << 7, h << 7, (min(h + 1, 127)) << 7 };
    int wx[3] = { max(w - 1, 0), w, min(w + 1, 127) };

    const short* xb = (const short*)xup + ((size_t)(b * HWD) << 8) + chunk * 8;
    float sum[8];
#pragma unroll
    for (int j = 0; j < 8; ++j) sum[j] = 0.f;
#pragma unroll
    for (int dy = 0; dy < 3; ++dy) {
#pragma unroll
        for (int dx = 0; dx < 3; ++dx) {
            float wgt = wk[dy * 3 + dx] * ymask[dy] * xmask[dx];
            short8 v = *(const short8*)(xb + ((size_t)(hy[dy] + wx[dx]) << 8));
#pragma unroll
            for (int j = 0; j < 8; ++j) sum[j] += wgt * s2f(v[j]);
        }
    }
    short8 pk;
#pragma unroll
    for (int j = 0; j < 8; ++j) pk[j] = f2s(sum[j]);
    *(short8*)((short*)xfilt + ((size_t)(b * HWD + hw) << 8) + chunk * 8) = pk;
}

// ---------------------------------------------------------------------------
// K6: trim_op -> out (b,256,16384) fp32
// ---------------------------------------------------------------------------
__global__ __launch_bounds__(256) void k6_trim(const bf16* __restrict__ xfilt,
        const float* __restrict__ toff, float* __restrict__ out)
{
    __shared__ float sm[32][260];
    int b = blockIdx.x >> 9;
    int hw0 = (blockIdx.x & 511) << 5;
    int wave = threadIdx.x >> 6, lane = threadIdx.x & 63;
    int e = lane * 4;
    int g = lane >> 4;
    const short* xb = (const short*)xfilt + ((size_t)(b * HWD) << 8);
    const float* tfx = toff + ((size_t)(b * 8 + 2 * g)     << 14);
    const float* tfy = toff + ((size_t)(b * 8 + 2 * g + 1) << 14);

    for (int i = 0; i < 8; ++i) {
        int pp = wave * 8 + i;
        int hw = hw0 + pp;
        int h = hw >> 7, w = hw & 127;
        float ox = tfx[hw], oy = tfy[hw];
        float ix = fminf(fmaxf(w + ox, 0.f), 127.f);
        float iy = fminf(fmaxf(h + oy, 0.f), 127.f);
        float x0f = floorf(ix), y0f = floorf(iy);
        float fx = ix - x0f, fy = iy - y0f;
        int x0 = (int)x0f, y0 = (int)y0f;
        int x1 = min(x0 + 1, 127), y1 = min(y0 + 1, 127);
        float w00 = (1.f - fx) * (1.f - fy), w01 = fx * (1.f - fy);
        float w10 = (1.f - fx) * fy,        w11 = fx * fy;
        short4v v00 = *(const short4v*)(xb + (((size_t)(y0 << 7) + x0) << 8) + e);
        short4v v01 = *(const short4v*)(xb + (((size_t)(y0 << 7) + x1) << 8) + e);
        short4v v10 = *(const short4v*)(xb + (((size_t)(y1 << 7) + x0) << 8) + e);
        short4v v11 = *(const short4v*)(xb + (((size_t)(y1 << 7) + x1) << 8) + e);
#pragma unroll
        for (int j = 0; j < 4; ++j) {
            sm[pp][e + j] = w00 * s2f(v00[j]) + w01 * s2f(v01[j])
                          + w10 * s2f(v10[j]) + w11 * s2f(v11[j]);
        }
    }
    __syncthreads();
    int lp = threadIdx.x & 31;
    int c0 = (threadIdx.x >> 5) << 5;
    float* ob = out + (((size_t)b << 8) << 14) + hw0 + lp;
#pragma unroll 8
    for (int k = 0; k < 32; ++k) {
        int c = c0 + k;
        ob[(size_t)c << 14] = sm[lp][c];
    }
}

extern "C" void kernel_launch(void* const* d_in, const int* in_sizes, int n_in,
                              void* d_out, int out_size, void* d_ws, size_t ws_size,
                              hipStream_t stream)
{
    const float* x       = (const float*)d_in[0];
    const float* w_off   = (const float*)d_in[1];
    const float* b_off   = (const float*)d_in[2];
    const float* w_ast   = (const float*)d_in[3];
    const float* b_ast   = (const float*)d_in[4];
    const float* comp_w  = (const float*)d_in[5];
    const float* comp_b  = (const float*)d_in[6];
    const float* filt_w  = (const float*)d_in[7];
    const float* filt_b  = (const float*)d_in[8];
    const float* trim_w  = (const float*)d_in[9];
    const float* trim_b  = (const float*)d_in[10];
    const float* trim_aw = (const float*)d_in[11];
    const float* trim_ab = (const float*)d_in[12];
    float* out = (float*)d_out;

    char* ws = (char*)d_ws;
    float* offpm = (float*)(ws);                 // 2 MiB (b,4096,32)
    bf16*  xup   = (bf16*) (ws + (2ull << 20));  // 32 MiB pixel-major (b,hw,256)
    bf16*  xpm   = (bf16*) (ws + (34ull << 20)); // 8 MiB pixel-major (b,4096,256)
    bf16*  xfilt = (bf16*) (ws + (50ull << 20)); // 32 MiB pixel-major (b,hw,256)
    float* toff  = (float*)(ws + (82ull << 20)); // 2 MiB (b,8,16384)
    bf16*  kern  = (bf16*) (ws + (84ull << 20)); // 2 MiB (b,hw,16) — own region
                                                 // (no longer aliases offpm: fused
                                                 // k23 blocks write kern while other
                                                 // blocks still read offpm)

    hipLaunchKernelGGL(k01_xpose_off, dim3(256),  dim3(256), 0, stream,
                       x, w_off, b_off, w_ast, b_ast, xpm, offpm);
    hipLaunchKernelGGL(k23_defsample_comp, dim3(1024), dim3(256), 0, stream,
                       xpm, offpm, comp_w, comp_b, filt_w, filt_b,
                       trim_w, trim_b, trim_aw, trim_ab, xup, kern, toff);
    hipLaunchKernelGGL(k4b_apply,   dim3(8192),  dim3(256), 0, stream,
                       xup, kern, xfilt);
    hipLaunchKernelGGL(k6_trim,     dim3(2048),  dim3(256), 0, stream,
                       xfilt, toff, out);
}